// Round 10
// baseline (1191.471 us; speedup 1.0000x reference)
//
#include <hip/hip_runtime.h>

constexpr int N = 100000;
constexpr int E = 1280000;
constexpr int C = 64;
constexpr int NB = (N + 255) / 256;   // 391 dst-buckets of 256 nodes
constexpr int EPB = 4096;             // edges per bin_k block
constexpr int NBIN = (E + EPB - 1) / EPB;  // 313

typedef __attribute__((ext_vector_type(8))) short bf16x8;
typedef __attribute__((ext_vector_type(4))) float f32x4;

// ---- bf16 helpers (RNE pack, bit-trick unpack) ----
__device__ __forceinline__ unsigned bfr(float v) {
    unsigned u = __float_as_uint(v);
    return (u + 0x7fffu + ((u >> 16) & 1u)) >> 16;
}
__device__ __forceinline__ float bflo(unsigned w) { return __uint_as_float(w << 16); }
__device__ __forceinline__ float bfhi(unsigned w) { return __uint_as_float(w & 0xffff0000u); }

// ---------------- cast x -> packed bf16 rows ----------------
__global__ __launch_bounds__(256) void cast_k(const float* __restrict__ x,
                                              uint2* __restrict__ xb) {
    int i = blockIdx.x * 256 + threadIdx.x;   // one uint2 (4 channels) per thread
    if (i < N * 16) {
        float4 v = ((const float4*)x)[i];
        uint2 o;
        o.x = bfr(v.x) | (bfr(v.y) << 16);
        o.y = bfr(v.z) | (bfr(v.w) << 16);
        xb[i] = o;
    }
}

// ---------------- cast Wl|Wr -> bf16 concat table Wb[64][128] ----------------
__global__ __launch_bounds__(256) void wcast_k(const float* __restrict__ Wl,
                                               const float* __restrict__ Wr,
                                               unsigned* __restrict__ Wb) {
    int u = blockIdx.x * 256 + threadIdx.x;   // one packed uint (2 bf16) per thread
    if (u < 64 * 64) {
        int c = u >> 5;        // 64 rows, 32 uints per half-row
        int p = u & 31;        // pair index within the 64-k half
        float2 l = *(const float2*)(Wl + c * 64 + p * 2);
        float2 r = *(const float2*)(Wr + c * 64 + p * 2);
        Wb[c * 64 + p]      = bfr(l.x) | (bfr(l.y) << 16);
        Wb[c * 64 + 32 + p] = bfr(r.x) | (bfr(r.y) << 16);
    }
}

// ---------------- stage 0: coarse histogram of dst>>8 ----------------
__global__ __launch_bounds__(256) void chist_k(const int* __restrict__ dst,
                                               int* __restrict__ bcnt) {
    __shared__ int h[NB];
    int t = threadIdx.x;
    for (int i = t; i < NB; i += 256) h[i] = 0;
    __syncthreads();
    int e0 = blockIdx.x * EPB;
    int eEnd = min(e0 + EPB, E);
    for (int e = e0 + t; e < eEnd; e += 256) atomicAdd(&h[dst[e] >> 8], 1);
    __syncthreads();
    for (int i = t; i < NB; i += 256)
        if (h[i]) atomicAdd(&bcnt[i], h[i]);
}

// ---------------- stage 1: scan bucket counts -> bases; zero cursors ----------------
__global__ __launch_bounds__(512) void scanB_k(const int* __restrict__ bcnt,
                                               int* __restrict__ bbase,
                                               int* __restrict__ gcur) {
    __shared__ int s[2][512];
    int t = threadIdx.x;
    int v = (t < NB) ? bcnt[t] : 0;
    s[0][t] = v;
    __syncthreads();
    int p = 0;
    for (int off = 1; off < 512; off <<= 1) {
        int a = s[p][t] + (t >= off ? s[p][t - off] : 0);
        s[p ^ 1][t] = a;
        p ^= 1;
        __syncthreads();
    }
    if (t < NB) { bbase[t] = s[p][t] - v; gcur[t] = 0; }
}

// ---------------- stage 2: bin edges into bucket-contiguous packed runs ----------------
// packed tmp entry: (src << 8) | (dst & 255)    [src < 2^17 fits bits 8..24]
__global__ __launch_bounds__(256) void bin_k(const int* __restrict__ src,
                                             const int* __restrict__ dst,
                                             const int* __restrict__ bbase,
                                             int* __restrict__ gcur,
                                             unsigned* __restrict__ tmp) {
    __shared__ int hist[NB];
    __shared__ int start[NB];
    __shared__ int cnt2[NB];
    __shared__ int gbase[NB];
    __shared__ unsigned pk[EPB];          // 16 KB
    __shared__ unsigned short bkt[EPB];   // 8 KB
    __shared__ int sc[2][512];
    int t = threadIdx.x;
    for (int i = t; i < NB; i += 256) { hist[i] = 0; cnt2[i] = 0; }
    __syncthreads();
    int e0 = blockIdx.x * EPB;
    int eEnd = min(e0 + EPB, E);
    for (int e = e0 + t; e < eEnd; e += 256) atomicAdd(&hist[dst[e] >> 8], 1);
    __syncthreads();
    sc[0][t]       = (t < NB) ? hist[t] : 0;
    sc[0][t + 256] = (t + 256 < NB) ? hist[t + 256] : 0;
    __syncthreads();
    int p = 0;
    for (int off = 1; off < 512; off <<= 1) {
        int a = sc[p][t]       + (t >= off ? sc[p][t - off] : 0);
        int b = sc[p][t + 256] + sc[p][t + 256 - off];
        sc[p ^ 1][t] = a;
        sc[p ^ 1][t + 256] = b;
        p ^= 1;
        __syncthreads();
    }
    if (t < NB)       start[t]       = sc[p][t]       - hist[t];
    if (t + 256 < NB) start[t + 256] = sc[p][t + 256] - hist[t + 256];
    __syncthreads();
    for (int e = e0 + t; e < eEnd; e += 256) {
        int d = dst[e];
        int b = d >> 8;
        int pos = start[b] + atomicAdd(&cnt2[b], 1);
        pk[pos] = ((unsigned)src[e] << 8) | (unsigned)(d & 255);
        bkt[pos] = (unsigned short)b;
    }
    __syncthreads();
    for (int i = t; i < NB; i += 256)
        gbase[i] = hist[i] ? bbase[i] + atomicAdd(&gcur[i], hist[i]) : 0;
    __syncthreads();
    int n = eEnd - e0;
    for (int i = t; i < n; i += 256) {
        int b = bkt[i];
        tmp[gbase[b] + (i - start[b])] = pk[i];
    }
}

// ------- aggregation v5: edge-parallel per bucket, LDS fp32 accumulation -------
// one block (8 waves) per 256-node bucket; entries streamed 4-per-wave;
// per edge: 16 lanes x uint2 = 128B contiguous row gather, 4 ds_add_f32/lane
// into padded sAgg[dst&255][65] (65 % 32 == 1 spreads banks; 2-way = free).
__global__ __launch_bounds__(512) void baggr_k(const unsigned* __restrict__ tmp,
                                               const int* __restrict__ bbase,
                                               const int* __restrict__ bcnt,
                                               const uint2* __restrict__ featb,  // [N][16]
                                               unsigned* __restrict__ aggb) {    // [N][32]
    __shared__ float sAgg[256][65];   // 66,560 B
    __shared__ int sCnt[256];
    int b = blockIdx.x;
    int base = bbase[b];
    int count = bcnt[b];
    int t = threadIdx.x;
    for (int i = t; i < 256 * 65; i += 512) ((float*)sAgg)[i] = 0.f;
    if (t < 256) sCnt[t] = 0;
    __syncthreads();

    int lane = t & 63;
    int w = t >> 6;            // wave 0..7
    int g = lane >> 4;         // entry slot 0..3
    int q = lane & 15;         // channel quad
    for (int i = w * 4 + g; i < count; i += 32) {
        unsigned e = tmp[base + i];
        int srcN = (int)(e >> 8);
        int dl = (int)(e & 255u);
        uint2 u = featb[(size_t)srcN * 16 + q];
        atomicAdd(&sAgg[dl][q * 4 + 0], bflo(u.x));
        atomicAdd(&sAgg[dl][q * 4 + 1], bfhi(u.x));
        atomicAdd(&sAgg[dl][q * 4 + 2], bflo(u.y));
        atomicAdd(&sAgg[dl][q * 4 + 3], bfhi(u.y));
        if (q == 0) atomicAdd(&sCnt[dl], 1);
    }
    __syncthreads();

    int nodeBase = b * 256;
    for (int i = t; i < 256 * 32; i += 512) {
        int r = i >> 5, pu = i & 31;
        int node = nodeBase + r;
        if (node < N) {
            int c = sCnt[r];
            float inv = c > 0 ? 1.f / (float)c : 0.f;
            unsigned o = bfr(sAgg[r][pu * 2] * inv) |
                         (bfr(sAgg[r][pu * 2 + 1] * inv) << 16);
            aggb[((size_t)node << 5) + pu] = o;
        }
    }
}

// ---------------- combine via MFMA: out = [agg|x] (K=128) * Wb^T + bias ----------------
// one wave per 16-node tile; 4 col-tiles x 4 K-chunks = 16 mfma_16x16x32_bf16.
template <int RELU, int OBF>
__global__ __launch_bounds__(256) void combine_mfma_k(
    const unsigned short* __restrict__ Ab,   // [N][64] bf16 agg
    const unsigned short* __restrict__ Xb,   // [N][64] bf16 root
    const unsigned short* __restrict__ Wb,   // [64][128] bf16 (Wl|Wr rows)
    const float* __restrict__ bias,
    float* __restrict__ outF, unsigned short* __restrict__ outB) {
    int wave = threadIdx.x >> 6;
    int lane = threadIdx.x & 63;
    int row0 = (blockIdx.x * 4 + wave) * 16;   // 16-node tile base
    if (row0 >= N) return;
    int g = lane >> 4;
    int r = lane & 15;
    int node = row0 + r;

    const unsigned short* arow = Ab + (size_t)node * 64 + g * 8;
    const unsigned short* xrow = Xb + (size_t)node * 64 + g * 8;
    bf16x8 a[4];
    a[0] = *(const bf16x8*)(const void*)(arow);
    a[1] = *(const bf16x8*)(const void*)(arow + 32);
    a[2] = *(const bf16x8*)(const void*)(xrow);
    a[3] = *(const bf16x8*)(const void*)(xrow + 32);

#pragma unroll
    for (int ct = 0; ct < 4; ++ct) {
        int c = ct * 16 + r;
        const unsigned short* wrow = Wb + (size_t)c * 128 + g * 8;
        f32x4 acc = {0.f, 0.f, 0.f, 0.f};
#pragma unroll
        for (int kc = 0; kc < 4; ++kc) {
            bf16x8 b = *(const bf16x8*)(const void*)(wrow + kc * 32);
            acc = __builtin_amdgcn_mfma_f32_16x16x32_bf16(a[kc], b, acc, 0, 0, 0);
        }
        float bs = bias[c];
#pragma unroll
        for (int rr = 0; rr < 4; ++rr) {
            int orow = row0 + g * 4 + rr;
            float v = acc[rr] + bs;
            if (RELU) v = fmaxf(v, 0.f);
            if (OBF) {
                float v1 = __shfl_xor(v, 1);    // neighbor column's value
                if ((lane & 1) == 0) {
                    unsigned u = bfr(v) | (bfr(v1) << 16);
                    *(unsigned*)(void*)(outB + (size_t)orow * 64 + c) = u;
                }
            } else {
                outF[(size_t)orow * 64 + c] = v;
            }
        }
    }
}

extern "C" void kernel_launch(void* const* d_in, const int* in_sizes, int n_in,
                              void* d_out, int out_size, void* d_ws, size_t ws_size,
                              hipStream_t stream) {
    const float* x   = (const float*)d_in[0];
    const int*   ei  = (const int*)d_in[1];
    const int*   srcI = ei;
    const int*   dstI = ei + E;
    const float* W1l = (const float*)d_in[2];
    const float* b1  = (const float*)d_in[3];
    const float* W1r = (const float*)d_in[4];
    const float* W2l = (const float*)d_in[5];
    const float* b2  = (const float*)d_in[6];
    const float* W2r = (const float*)d_in[7];
    float* out = (float*)d_out;

    // workspace layout (4B units)
    int*            bcnt  = (int*)d_ws;                    // 512
    int*            bbase = bcnt + 512;                    // 512
    int*            gcur  = bbase + 512;                   // 512
    unsigned*       tmp   = (unsigned*)(gcur + 512);       // E packed entries (5.12 MB, persistent)
    unsigned short* aggb  = (unsigned short*)(tmp + E);    // N*64 bf16 (12.8 MB)
    unsigned short* xb    = aggb + (size_t)N * 64;         // N*64 bf16
    unsigned short* hb    = xb + (size_t)N * 64;           // N*64 bf16
    unsigned*       Wb1   = (unsigned*)(hb + (size_t)N * 64);  // 16 KB
    unsigned*       Wb2   = Wb1 + 64 * 64;                     // 16 KB

    hipMemsetAsync(bcnt, 0, 512 * sizeof(int), stream);

    cast_k<<<(N * 16 + 255) / 256, 256, 0, stream>>>(x, (uint2*)xb);
    wcast_k<<<16, 256, 0, stream>>>(W1l, W1r, Wb1);
    wcast_k<<<16, 256, 0, stream>>>(W2l, W2r, Wb2);
    chist_k<<<NBIN, 256, 0, stream>>>(dstI, bcnt);
    scanB_k<<<1, 512, 0, stream>>>(bcnt, bbase, gcur);
    bin_k<<<NBIN, 256, 0, stream>>>(srcI, dstI, bbase, gcur, tmp);

    const int nMfmaBlocks = (N / 16 + 3) / 4;   // 1563

    // ---- layer 1 ----
    baggr_k<<<NB, 512, 0, stream>>>(tmp, bbase, bcnt, (const uint2*)xb, (unsigned*)aggb);
    combine_mfma_k<1, 1><<<nMfmaBlocks, 256, 0, stream>>>(
        aggb, xb, (const unsigned short*)Wb1, b1, nullptr, hb);

    // ---- layer 2 ----
    baggr_k<<<NB, 512, 0, stream>>>(tmp, bbase, bcnt, (const uint2*)hb, (unsigned*)aggb);
    combine_mfma_k<0, 0><<<nMfmaBlocks, 256, 0, stream>>>(
        aggb, hb, (const unsigned short*)Wb2, b2, out, nullptr);
}

// Round 12
// 168.852 us; speedup vs baseline: 7.0563x; 7.0563x over previous
//
#include <hip/hip_runtime.h>

constexpr int N = 100000;
constexpr int E = 1280000;
constexpr int C = 64;
constexpr int NB = (N + 255) / 256;   // 391 dst-buckets of 256 nodes
constexpr int EPB = 4096;             // edges per chist block
constexpr int NBIN = (E + EPB - 1) / EPB;   // 313
constexpr int EPB2 = 8192;            // edges per bin_k block
constexpr int NBIN2 = (E + EPB2 - 1) / EPB2; // 157
constexpr int CAP = 4096;             // bucket capacity (avg 3274, max ~3.6k)

typedef __attribute__((ext_vector_type(8))) short bf16x8;
typedef __attribute__((ext_vector_type(4))) float f32x4;

// ---- bf16 helpers (RNE pack, bit-trick unpack) ----
__device__ __forceinline__ unsigned bfr(float v) {
    unsigned u = __float_as_uint(v);
    return (u + 0x7fffu + ((u >> 16) & 1u)) >> 16;
}
__device__ __forceinline__ float bflo(unsigned w) { return __uint_as_float(w << 16); }
__device__ __forceinline__ float bfhi(unsigned w) { return __uint_as_float(w & 0xffff0000u); }

// ---------------- fused prep: cast x | cast W1 | cast W2 | coarse hist ----------------
constexpr int CASTB = (N * 16 + 255) / 256;   // 6250
constexpr int WCB = 8;   // blocks per weight table: 8*256 = 2048 = 64 rows x 32 uint-pairs
__global__ __launch_bounds__(256) void prep_k(
    const float* __restrict__ x, uint2* __restrict__ xb,
    const float* __restrict__ W1l, const float* __restrict__ W1r, unsigned* __restrict__ Wb1,
    const float* __restrict__ W2l, const float* __restrict__ W2r, unsigned* __restrict__ Wb2,
    const int* __restrict__ dst, int* __restrict__ bcnt) {
    int blk = blockIdx.x;
    int t = threadIdx.x;
    if (blk < CASTB) {                         // ---- cast x -> bf16 ----
        int i = blk * 256 + t;
        if (i < N * 16) {
            float4 v = ((const float4*)x)[i];
            uint2 o;
            o.x = bfr(v.x) | (bfr(v.y) << 16);
            o.y = bfr(v.z) | (bfr(v.w) << 16);
            xb[i] = o;
        }
        return;
    }
    if (blk < CASTB + 2 * WCB) {               // ---- cast weights (2048 items each) ----
        int wb = blk - CASTB;                  // 0..15
        const float* Wl = (wb < WCB) ? W1l : W2l;
        const float* Wr = (wb < WCB) ? W1r : W2r;
        unsigned* Wb = (wb < WCB) ? Wb1 : Wb2;
        int u = ((wb < WCB) ? wb : wb - WCB) * 256 + t;   // 0..2047
        int c = u >> 5;        // row 0..63
        int p = u & 31;        // uint-pair 0..31 within the 64-k half
        float2 l = *(const float2*)(Wl + c * 64 + p * 2);
        float2 r = *(const float2*)(Wr + c * 64 + p * 2);
        Wb[c * 64 + p]      = bfr(l.x) | (bfr(l.y) << 16);
        Wb[c * 64 + 32 + p] = bfr(r.x) | (bfr(r.y) << 16);
        return;
    }
    // ---- coarse histogram of dst>>8 ----
    __shared__ int h[NB];
    int cb = blk - CASTB - 2 * WCB;
    for (int i = t; i < NB; i += 256) h[i] = 0;
    __syncthreads();
    int e0 = cb * EPB;
    int eEnd = min(e0 + EPB, E);
    for (int e = e0 + t; e < eEnd; e += 256) atomicAdd(&h[dst[e] >> 8], 1);
    __syncthreads();
    for (int i = t; i < NB; i += 256)
        if (h[i]) atomicAdd(&bcnt[i], h[i]);
}

// ---------------- stage 1: scan bucket counts -> bases; zero cursors ----------------
__global__ __launch_bounds__(512) void scanB_k(const int* __restrict__ bcnt,
                                               int* __restrict__ bbase,
                                               int* __restrict__ gcur) {
    __shared__ int s[2][512];
    int t = threadIdx.x;
    int v = (t < NB) ? bcnt[t] : 0;
    s[0][t] = v;
    __syncthreads();
    int p = 0;
    for (int off = 1; off < 512; off <<= 1) {
        int a = s[p][t] + (t >= off ? s[p][t - off] : 0);
        s[p ^ 1][t] = a;
        p ^= 1;
        __syncthreads();
    }
    if (t < NB) { bbase[t] = s[p][t] - v; gcur[t] = 0; }
}

// ---------------- stage 2: bin edges into bucket-contiguous packed runs ----------------
// packed tmp entry: (src << 8) | (dst & 255)    [src < 2^17 fits bits 8..24]
__global__ __launch_bounds__(512) void bin_k(const int* __restrict__ src,
                                             const int* __restrict__ dst,
                                             const int* __restrict__ bbase,
                                             int* __restrict__ gcur,
                                             unsigned* __restrict__ tmp) {
    __shared__ int hist[NB];
    __shared__ int start[NB];
    __shared__ int cnt2[NB];
    __shared__ int gbase[NB];
    __shared__ unsigned pk[EPB2];          // 32 KB
    __shared__ unsigned short bkt[EPB2];   // 16 KB
    __shared__ int sc[2][512];
    int t = threadIdx.x;
    for (int i = t; i < NB; i += 512) { hist[i] = 0; cnt2[i] = 0; }
    __syncthreads();
    int e0 = blockIdx.x * EPB2;
    int eEnd = min(e0 + EPB2, E);
    for (int e = e0 + t; e < eEnd; e += 512) atomicAdd(&hist[dst[e] >> 8], 1);
    __syncthreads();
    int v = (t < NB) ? hist[t] : 0;
    sc[0][t] = v;
    __syncthreads();
    int p = 0;
    for (int off = 1; off < 512; off <<= 1) {
        int a = sc[p][t] + (t >= off ? sc[p][t - off] : 0);
        sc[p ^ 1][t] = a;
        p ^= 1;
        __syncthreads();
    }
    if (t < NB) start[t] = sc[p][t] - v;
    __syncthreads();
    for (int e = e0 + t; e < eEnd; e += 512) {
        int d = dst[e];
        int b = d >> 8;
        int pos = start[b] + atomicAdd(&cnt2[b], 1);
        pk[pos] = ((unsigned)src[e] << 8) | (unsigned)(d & 255);
        bkt[pos] = (unsigned short)b;
    }
    __syncthreads();
    for (int i = t; i < NB; i += 512)
        gbase[i] = hist[i] ? bbase[i] + atomicAdd(&gcur[i], hist[i]) : 0;
    __syncthreads();
    int n = eEnd - e0;
    for (int i = t; i < n; i += 512) {
        int b = bkt[i];
        tmp[gbase[b] + (i - start[b])] = pk[i];
    }
}

// ---------------- stage 3: per-bucket counting sort -> rowp/deg/csr ----------------
__global__ __launch_bounds__(512) void bsort_k(const unsigned* __restrict__ tmp,
                                               const int* __restrict__ bbase,
                                               const int* __restrict__ bcnt,
                                               int* __restrict__ rowp,
                                               int* __restrict__ deg,
                                               int* __restrict__ csr) {
    int b = blockIdx.x;
    int base = bbase[b];
    int count = bcnt[b];
    __shared__ int h[256], st[256], c2[256];
    __shared__ int sc[2][256];
    __shared__ unsigned srcA[CAP];   // 16 KB
    int t = threadIdx.x;
    if (t < 256) { h[t] = 0; c2[t] = 0; }
    __syncthreads();
    for (int i = t; i < count; i += 512) atomicAdd(&h[tmp[base + i] & 255u], 1);
    __syncthreads();
    if (t < 256) sc[0][t] = h[t];
    __syncthreads();
    int p = 0;
    for (int off = 1; off < 256; off <<= 1) {
        if (t < 256) sc[p ^ 1][t] = sc[p][t] + (t >= off ? sc[p][t - off] : 0);
        p ^= 1;
        __syncthreads();
    }
    if (t < 256) {
        int excl = sc[p][t] - h[t];
        st[t] = excl;
        int node = b * 256 + t;
        if (node < N) { rowp[node] = base + excl; deg[node] = h[t]; }
    }
    __syncthreads();
    for (int i = t; i < count; i += 512) {
        unsigned pr = tmp[base + i];
        int d = (int)(pr & 255u);
        int pos = st[d] + atomicAdd(&c2[d], 1);
        srcA[pos] = pr >> 8;
    }
    __syncthreads();
    for (int i = t; i < count; i += 512) csr[base + i] = (int)srcA[i];
}

// ------- aggregation (R7-proven): one wave/node, 4 edge-groups x 16 lanes x uint2 -------
// output: mean, packed bf16 row-major [N][64]
__global__ __launch_bounds__(256) void agg_k(const int* __restrict__ csr,
                                             const int* __restrict__ rowp,
                                             const int* __restrict__ deg,
                                             const uint2* __restrict__ featb,
                                             uint2* __restrict__ aggb) {
    int node = blockIdx.x * 4 + (threadIdx.x >> 6);
    int lane = threadIdx.x & 63;
    int g = lane >> 4;            // edge slot 0..3
    int q = lane & 15;            // channel quad index
    int start = rowp[node];
    int d = deg[node];
    float4 acc = make_float4(0.f, 0.f, 0.f, 0.f);
    int j = g;
    for (; j + 4 < d; j += 8) {   // 8 edges in flight per wave
        int s0 = csr[start + j];
        int s1 = csr[start + j + 4];
        uint2 u0 = featb[(size_t)s0 * 16 + q];
        uint2 u1 = featb[(size_t)s1 * 16 + q];
        acc.x += bflo(u0.x) + bflo(u1.x);
        acc.y += bfhi(u0.x) + bfhi(u1.x);
        acc.z += bflo(u0.y) + bflo(u1.y);
        acc.w += bfhi(u0.y) + bfhi(u1.y);
    }
    for (; j < d; j += 4) {
        int s0 = csr[start + j];
        uint2 u0 = featb[(size_t)s0 * 16 + q];
        acc.x += bflo(u0.x); acc.y += bfhi(u0.x);
        acc.z += bflo(u0.y); acc.w += bfhi(u0.y);
    }
#pragma unroll
    for (int off = 16; off <= 32; off <<= 1) {
        acc.x += __shfl_xor(acc.x, off);
        acc.y += __shfl_xor(acc.y, off);
        acc.z += __shfl_xor(acc.z, off);
        acc.w += __shfl_xor(acc.w, off);
    }
    if (g == 0) {
        float inv = d > 0 ? 1.f / (float)d : 0.f;
        uint2 o;
        o.x = bfr(acc.x * inv) | (bfr(acc.y * inv) << 16);
        o.y = bfr(acc.z * inv) | (bfr(acc.w * inv) << 16);
        aggb[(size_t)node * 16 + q] = o;
    }
}

// ---------------- combine via MFMA: out = [agg|x] (K=128) * Wb^T + bias ----------------
// one wave per 16-node tile; 4 col-tiles x 4 K-chunks = 16 mfma_16x16x32_bf16.
template <int RELU, int OBF>
__global__ __launch_bounds__(256) void combine_mfma_k(
    const unsigned short* __restrict__ Ab,   // [N][64] bf16 agg
    const unsigned short* __restrict__ Xb,   // [N][64] bf16 root
    const unsigned short* __restrict__ Wb,   // [64][128] bf16 (Wl|Wr rows)
    const float* __restrict__ bias,
    float* __restrict__ outF, unsigned short* __restrict__ outB) {
    int wave = threadIdx.x >> 6;
    int lane = threadIdx.x & 63;
    int row0 = (blockIdx.x * 4 + wave) * 16;   // 16-node tile base
    if (row0 >= N) return;
    int g = lane >> 4;
    int r = lane & 15;
    int node = row0 + r;

    const unsigned short* arow = Ab + (size_t)node * 64 + g * 8;
    const unsigned short* xrow = Xb + (size_t)node * 64 + g * 8;
    bf16x8 a[4];
    a[0] = *(const bf16x8*)(const void*)(arow);
    a[1] = *(const bf16x8*)(const void*)(arow + 32);
    a[2] = *(const bf16x8*)(const void*)(xrow);
    a[3] = *(const bf16x8*)(const void*)(xrow + 32);

#pragma unroll
    for (int ct = 0; ct < 4; ++ct) {
        int c = ct * 16 + r;
        const unsigned short* wrow = Wb + (size_t)c * 128 + g * 8;
        f32x4 acc = {0.f, 0.f, 0.f, 0.f};
#pragma unroll
        for (int kc = 0; kc < 4; ++kc) {
            bf16x8 b = *(const bf16x8*)(const void*)(wrow + kc * 32);
            acc = __builtin_amdgcn_mfma_f32_16x16x32_bf16(a[kc], b, acc, 0, 0, 0);
        }
        float bs = bias[c];
#pragma unroll
        for (int rr = 0; rr < 4; ++rr) {
            int orow = row0 + g * 4 + rr;
            float v = acc[rr] + bs;
            if (RELU) v = fmaxf(v, 0.f);
            if (OBF) {
                float v1 = __shfl_xor(v, 1);    // neighbor column's value
                if ((lane & 1) == 0) {
                    unsigned u = bfr(v) | (bfr(v1) << 16);
                    *(unsigned*)(void*)(outB + (size_t)orow * 64 + c) = u;
                }
            } else {
                outF[(size_t)orow * 64 + c] = v;
            }
        }
    }
}

extern "C" void kernel_launch(void* const* d_in, const int* in_sizes, int n_in,
                              void* d_out, int out_size, void* d_ws, size_t ws_size,
                              hipStream_t stream) {
    const float* x   = (const float*)d_in[0];
    const int*   ei  = (const int*)d_in[1];
    const int*   srcI = ei;
    const int*   dstI = ei + E;
    const float* W1l = (const float*)d_in[2];
    const float* b1  = (const float*)d_in[3];
    const float* W1r = (const float*)d_in[4];
    const float* W2l = (const float*)d_in[5];
    const float* b2  = (const float*)d_in[6];
    const float* W2r = (const float*)d_in[7];
    float* out = (float*)d_out;

    // workspace layout (4B units)
    int*            bcnt  = (int*)d_ws;                    // 512
    int*            bbase = bcnt + 512;                    // 512
    int*            gcur  = bbase + 512;                   // 512
    int*            deg   = gcur + 512;                    // 102400
    int*            rowp  = deg + 102400;                  // 102400
    int*            csr   = rowp + 102400;                 // E
    unsigned short* aggb  = (unsigned short*)(csr + E);    // N*64 bf16 (12.8 MB)
    unsigned short* xb    = aggb + (size_t)N * 64;         // N*64 bf16
    unsigned short* hb    = xb + (size_t)N * 64;           // N*64 bf16
    unsigned*       Wb1   = (unsigned*)(hb + (size_t)N * 64);  // 16 KB
    unsigned*       Wb2   = Wb1 + 64 * 64;                     // 16 KB
    unsigned*       tmp   = (unsigned*)aggb;               // 5.12 MB overlay, consumed before aggb written

    hipMemsetAsync(bcnt, 0, 512 * sizeof(int), stream);

    prep_k<<<CASTB + 2 * WCB + NBIN, 256, 0, stream>>>(
        x, (uint2*)xb, W1l, W1r, Wb1, W2l, W2r, Wb2, dstI, bcnt);
    scanB_k<<<1, 512, 0, stream>>>(bcnt, bbase, gcur);
    bin_k<<<NBIN2, 512, 0, stream>>>(srcI, dstI, bbase, gcur, tmp);
    bsort_k<<<NB, 512, 0, stream>>>(tmp, bbase, bcnt, rowp, deg, csr);

    const int nAggBlocks = N / 4;               // 25000
    const int nMfmaBlocks = (N / 16 + 3) / 4;   // 1563

    // ---- layer 1 ----
    agg_k<<<nAggBlocks, 256, 0, stream>>>(csr, rowp, deg, (const uint2*)xb, (uint2*)aggb);
    combine_mfma_k<1, 1><<<nMfmaBlocks, 256, 0, stream>>>(
        aggb, xb, (const unsigned short*)Wb1, b1, nullptr, hb);

    // ---- layer 2 ----
    agg_k<<<nAggBlocks, 256, 0, stream>>>(csr, rowp, deg, (const uint2*)hb, (uint2*)aggb);
    combine_mfma_k<0, 0><<<nMfmaBlocks, 256, 0, stream>>>(
        aggb, hb, (const unsigned short*)Wb2, b2, out, nullptr);
}

// Round 13
// 159.915 us; speedup vs baseline: 7.4507x; 1.0559x over previous
//
#include <hip/hip_runtime.h>

constexpr int N = 100000;
constexpr int E = 1280000;
constexpr int C = 64;
constexpr int NB = (N + 255) / 256;   // 391 dst-buckets of 256 nodes
constexpr int EPB = 4096;             // edges per chist block
constexpr int NBIN = (E + EPB - 1) / EPB;   // 313
constexpr int EPB2 = 8192;            // edges per bin_k block
constexpr int NBIN2 = (E + EPB2 - 1) / EPB2; // 157
constexpr int CAP = 4096;             // bucket capacity (avg 3274, max ~3.6k)

typedef __attribute__((ext_vector_type(8))) short bf16x8;
typedef __attribute__((ext_vector_type(4))) float f32x4;

// ---- bf16 helpers (RNE pack, bit-trick unpack) ----
__device__ __forceinline__ unsigned bfr(float v) {
    unsigned u = __float_as_uint(v);
    return (u + 0x7fffu + ((u >> 16) & 1u)) >> 16;
}
__device__ __forceinline__ float bflo(unsigned w) { return __uint_as_float(w << 16); }
__device__ __forceinline__ float bfhi(unsigned w) { return __uint_as_float(w & 0xffff0000u); }

// ---------------- fused prep: cast x | cast W1 | cast W2 | coarse hist ----------------
constexpr int CASTB = (N * 16 + 255) / 256;   // 6250
constexpr int WCB = 8;   // blocks per weight table: 8*256 = 2048 = 64 rows x 32 uint-pairs
__global__ __launch_bounds__(256) void prep_k(
    const float* __restrict__ x, uint2* __restrict__ xb,
    const float* __restrict__ W1l, const float* __restrict__ W1r, unsigned* __restrict__ Wb1,
    const float* __restrict__ W2l, const float* __restrict__ W2r, unsigned* __restrict__ Wb2,
    const int* __restrict__ dst, int* __restrict__ bcnt) {
    int blk = blockIdx.x;
    int t = threadIdx.x;
    if (blk < CASTB) {                         // ---- cast x -> bf16 ----
        int i = blk * 256 + t;
        if (i < N * 16) {
            float4 v = ((const float4*)x)[i];
            uint2 o;
            o.x = bfr(v.x) | (bfr(v.y) << 16);
            o.y = bfr(v.z) | (bfr(v.w) << 16);
            xb[i] = o;
        }
        return;
    }
    if (blk < CASTB + 2 * WCB) {               // ---- cast weights (2048 items each) ----
        int wb = blk - CASTB;                  // 0..15
        const float* Wl = (wb < WCB) ? W1l : W2l;
        const float* Wr = (wb < WCB) ? W1r : W2r;
        unsigned* Wb = (wb < WCB) ? Wb1 : Wb2;
        int u = ((wb < WCB) ? wb : wb - WCB) * 256 + t;   // 0..2047
        int c = u >> 5;        // row 0..63
        int p = u & 31;        // uint-pair 0..31 within the 64-k half
        float2 l = *(const float2*)(Wl + c * 64 + p * 2);
        float2 r = *(const float2*)(Wr + c * 64 + p * 2);
        Wb[c * 64 + p]      = bfr(l.x) | (bfr(l.y) << 16);
        Wb[c * 64 + 32 + p] = bfr(r.x) | (bfr(r.y) << 16);
        return;
    }
    // ---- coarse histogram of dst>>8 ----
    __shared__ int h[NB];
    int cb = blk - CASTB - 2 * WCB;
    for (int i = t; i < NB; i += 256) h[i] = 0;
    __syncthreads();
    int e0 = cb * EPB;
    int eEnd = min(e0 + EPB, E);
    for (int e = e0 + t; e < eEnd; e += 256) atomicAdd(&h[dst[e] >> 8], 1);
    __syncthreads();
    for (int i = t; i < NB; i += 256)
        if (h[i]) atomicAdd(&bcnt[i], h[i]);
}

// ---------------- stage 1: scan bucket counts -> bases; zero cursors ----------------
__global__ __launch_bounds__(512) void scanB_k(const int* __restrict__ bcnt,
                                               int* __restrict__ bbase,
                                               int* __restrict__ gcur) {
    __shared__ int s[2][512];
    int t = threadIdx.x;
    int v = (t < NB) ? bcnt[t] : 0;
    s[0][t] = v;
    __syncthreads();
    int p = 0;
    for (int off = 1; off < 512; off <<= 1) {
        int a = s[p][t] + (t >= off ? s[p][t - off] : 0);
        s[p ^ 1][t] = a;
        p ^= 1;
        __syncthreads();
    }
    if (t < NB) { bbase[t] = s[p][t] - v; gcur[t] = 0; }
}

// ---------------- stage 2: bin edges into bucket-contiguous packed runs ----------------
// packed tmp entry: (src << 8) | (dst & 255)    [src < 2^17 fits bits 8..24]
__global__ __launch_bounds__(512) void bin_k(const int* __restrict__ src,
                                             const int* __restrict__ dst,
                                             const int* __restrict__ bbase,
                                             int* __restrict__ gcur,
                                             unsigned* __restrict__ tmp) {
    __shared__ int hist[NB];
    __shared__ int start[NB];
    __shared__ int cnt2[NB];
    __shared__ int gbase[NB];
    __shared__ unsigned pk[EPB2];          // 32 KB
    __shared__ unsigned short bkt[EPB2];   // 16 KB
    __shared__ int sc[2][512];
    int t = threadIdx.x;
    for (int i = t; i < NB; i += 512) { hist[i] = 0; cnt2[i] = 0; }
    __syncthreads();
    int e0 = blockIdx.x * EPB2;
    int eEnd = min(e0 + EPB2, E);
    for (int e = e0 + t; e < eEnd; e += 512) atomicAdd(&hist[dst[e] >> 8], 1);
    __syncthreads();
    int v = (t < NB) ? hist[t] : 0;
    sc[0][t] = v;
    __syncthreads();
    int p = 0;
    for (int off = 1; off < 512; off <<= 1) {
        int a = sc[p][t] + (t >= off ? sc[p][t - off] : 0);
        sc[p ^ 1][t] = a;
        p ^= 1;
        __syncthreads();
    }
    if (t < NB) start[t] = sc[p][t] - v;
    __syncthreads();
    for (int e = e0 + t; e < eEnd; e += 512) {
        int d = dst[e];
        int b = d >> 8;
        int pos = start[b] + atomicAdd(&cnt2[b], 1);
        pk[pos] = ((unsigned)src[e] << 8) | (unsigned)(d & 255);
        bkt[pos] = (unsigned short)b;
    }
    __syncthreads();
    for (int i = t; i < NB; i += 512)
        gbase[i] = hist[i] ? bbase[i] + atomicAdd(&gcur[i], hist[i]) : 0;
    __syncthreads();
    int n = eEnd - e0;
    for (int i = t; i < n; i += 512) {
        int b = bkt[i];
        tmp[gbase[b] + (i - start[b])] = pk[i];
    }
}

// ---------------- stage 3: per-bucket counting sort -> rowp/deg/csr ----------------
__global__ __launch_bounds__(512) void bsort_k(const unsigned* __restrict__ tmp,
                                               const int* __restrict__ bbase,
                                               const int* __restrict__ bcnt,
                                               int* __restrict__ rowp,
                                               int* __restrict__ deg,
                                               int* __restrict__ csr) {
    int b = blockIdx.x;
    int base = bbase[b];
    int count = bcnt[b];
    __shared__ int h[256], st[256], c2[256];
    __shared__ int sc[2][256];
    __shared__ unsigned srcA[CAP];   // 16 KB
    int t = threadIdx.x;
    if (t < 256) { h[t] = 0; c2[t] = 0; }
    __syncthreads();
    for (int i = t; i < count; i += 512) atomicAdd(&h[tmp[base + i] & 255u], 1);
    __syncthreads();
    if (t < 256) sc[0][t] = h[t];
    __syncthreads();
    int p = 0;
    for (int off = 1; off < 256; off <<= 1) {
        if (t < 256) sc[p ^ 1][t] = sc[p][t] + (t >= off ? sc[p][t - off] : 0);
        p ^= 1;
        __syncthreads();
    }
    if (t < 256) {
        int excl = sc[p][t] - h[t];
        st[t] = excl;
        int node = b * 256 + t;
        if (node < N) { rowp[node] = base + excl; deg[node] = h[t]; }
    }
    __syncthreads();
    for (int i = t; i < count; i += 512) {
        unsigned pr = tmp[base + i];
        int d = (int)(pr & 255u);
        int pos = st[d] + atomicAdd(&c2[d], 1);
        srcA[pos] = pr >> 8;
    }
    __syncthreads();
    for (int i = t; i < count; i += 512) csr[base + i] = (int)srcA[i];
}

// ------- fused aggregate + combine: one block per 16-node tile -------
// Phase A (per wave w): aggregate nodes tile+w*4+{0..3} (R12-proven loop),
//   pack bf16 mean rows into LDS sAgg[16][72] (pad 72 ushorts = 144B stride).
// Phase B (per wave w): col-tile ct = w of the 16x64 output:
//   A-frags from sAgg (agg) + global Fb (root), B-frags from Wb; 4 MFMA.
template <int RELU, int OBF>
__global__ __launch_bounds__(256) void aggcomb_k(
    const int* __restrict__ csr, const int* __restrict__ rowp,
    const int* __restrict__ deg,
    const unsigned short* __restrict__ Fb,   // [N][64] bf16 input features
    const unsigned short* __restrict__ Wb,   // [64][128] bf16 (Wl|Wr rows)
    const float* __restrict__ bias,
    float* __restrict__ outF, unsigned short* __restrict__ outB) {
    __shared__ unsigned short sAgg[16][72];
    const uint2* featb = (const uint2*)Fb;
    int tile = blockIdx.x * 16;              // N = 16 * 6250 exact
    int w = threadIdx.x >> 6;
    int lane = threadIdx.x & 63;
    int g = lane >> 4;            // edge slot / k-chunk 0..3
    int q = lane & 15;            // channel quad / tile row

    // ---- phase A: aggregation ----
    for (int s = 0; s < 4; ++s) {
        int node = tile + w * 4 + s;
        int start = rowp[node];
        int d = deg[node];
        float4 acc = make_float4(0.f, 0.f, 0.f, 0.f);
        int j = g;
        for (; j + 4 < d; j += 8) {
            int s0 = csr[start + j];
            int s1 = csr[start + j + 4];
            uint2 u0 = featb[(size_t)s0 * 16 + q];
            uint2 u1 = featb[(size_t)s1 * 16 + q];
            acc.x += bflo(u0.x) + bflo(u1.x);
            acc.y += bfhi(u0.x) + bfhi(u1.x);
            acc.z += bflo(u0.y) + bflo(u1.y);
            acc.w += bfhi(u0.y) + bfhi(u1.y);
        }
        for (; j < d; j += 4) {
            int s0 = csr[start + j];
            uint2 u0 = featb[(size_t)s0 * 16 + q];
            acc.x += bflo(u0.x); acc.y += bfhi(u0.x);
            acc.z += bflo(u0.y); acc.w += bfhi(u0.y);
        }
#pragma unroll
        for (int off = 16; off <= 32; off <<= 1) {
            acc.x += __shfl_xor(acc.x, off);
            acc.y += __shfl_xor(acc.y, off);
            acc.z += __shfl_xor(acc.z, off);
            acc.w += __shfl_xor(acc.w, off);
        }
        if (g == 0) {
            float inv = d > 0 ? 1.f / (float)d : 0.f;
            uint2 o;
            o.x = bfr(acc.x * inv) | (bfr(acc.y * inv) << 16);
            o.y = bfr(acc.z * inv) | (bfr(acc.w * inv) << 16);
            *(uint2*)&sAgg[w * 4 + s][q * 4] = o;
        }
    }
    __syncthreads();

    // ---- phase B: combine (wave w = col-tile w) ----
    int r = q;                    // row within tile = lane & 15
    int node = tile + r;
    const unsigned short* xrow = Fb + (size_t)node * 64 + g * 8;
    bf16x8 a[4];
    a[0] = *(const bf16x8*)(const void*)&sAgg[r][g * 8];
    a[1] = *(const bf16x8*)(const void*)&sAgg[r][32 + g * 8];
    a[2] = *(const bf16x8*)(const void*)(xrow);
    a[3] = *(const bf16x8*)(const void*)(xrow + 32);

    int c = w * 16 + r;
    const unsigned short* wrow = Wb + (size_t)c * 128 + g * 8;
    f32x4 acc = {0.f, 0.f, 0.f, 0.f};
#pragma unroll
    for (int kc = 0; kc < 4; ++kc) {
        bf16x8 b = *(const bf16x8*)(const void*)(wrow + kc * 32);
        acc = __builtin_amdgcn_mfma_f32_16x16x32_bf16(a[kc], b, acc, 0, 0, 0);
    }
    float bs = bias[c];
#pragma unroll
    for (int rr = 0; rr < 4; ++rr) {
        int orow = tile + g * 4 + rr;
        float v = acc[rr] + bs;
        if (RELU) v = fmaxf(v, 0.f);
        if (OBF) {
            float v1 = __shfl_xor(v, 1);    // neighbor column's value
            if ((lane & 1) == 0) {
                unsigned u = bfr(v) | (bfr(v1) << 16);
                *(unsigned*)(void*)(outB + (size_t)orow * 64 + c) = u;
            }
        } else {
            outF[(size_t)orow * 64 + c] = v;
        }
    }
}

extern "C" void kernel_launch(void* const* d_in, const int* in_sizes, int n_in,
                              void* d_out, int out_size, void* d_ws, size_t ws_size,
                              hipStream_t stream) {
    const float* x   = (const float*)d_in[0];
    const int*   ei  = (const int*)d_in[1];
    const int*   srcI = ei;
    const int*   dstI = ei + E;
    const float* W1l = (const float*)d_in[2];
    const float* b1  = (const float*)d_in[3];
    const float* W1r = (const float*)d_in[4];
    const float* W2l = (const float*)d_in[5];
    const float* b2  = (const float*)d_in[6];
    const float* W2r = (const float*)d_in[7];
    float* out = (float*)d_out;

    // workspace layout (4B units)
    int*            bcnt  = (int*)d_ws;                    // 512
    int*            bbase = bcnt + 512;                    // 512
    int*            gcur  = bbase + 512;                   // 512
    int*            deg   = gcur + 512;                    // 102400
    int*            rowp  = deg + 102400;                  // 102400
    int*            csr   = rowp + 102400;                 // E
    unsigned*       tmp   = (unsigned*)(csr + E);          // E (5.12 MB)
    unsigned short* xb    = (unsigned short*)(tmp + E);    // N*64 bf16 (12.8 MB)
    unsigned short* hb    = xb + (size_t)N * 64;           // N*64 bf16
    unsigned*       Wb1   = (unsigned*)(hb + (size_t)N * 64);  // 16 KB
    unsigned*       Wb2   = Wb1 + 64 * 64;                     // 16 KB

    hipMemsetAsync(bcnt, 0, 512 * sizeof(int), stream);

    prep_k<<<CASTB + 2 * WCB + NBIN, 256, 0, stream>>>(
        x, (uint2*)xb, W1l, W1r, Wb1, W2l, W2r, Wb2, dstI, bcnt);
    scanB_k<<<1, 512, 0, stream>>>(bcnt, bbase, gcur);
    bin_k<<<NBIN2, 512, 0, stream>>>(srcI, dstI, bbase, gcur, tmp);
    bsort_k<<<NB, 512, 0, stream>>>(tmp, bbase, bcnt, rowp, deg, csr);

    const int nTileBlocks = N / 16;   // 6250

    // ---- layer 1: h = relu(sage(xb)) -> bf16 hb ----
    aggcomb_k<1, 1><<<nTileBlocks, 256, 0, stream>>>(
        csr, rowp, deg, xb, (const unsigned short*)Wb1, b1, nullptr, hb);

    // ---- layer 2: out = sage(hb) -> fp32 ----
    aggcomb_k<0, 0><<<nTileBlocks, 256, 0, stream>>>(
        csr, rowp, deg, hb, (const unsigned short*)Wb2, b2, out, nullptr);
}